// Round 1
// baseline (2312.460 us; speedup 1.0000x reference)
//
#include <hip/hip_runtime.h>
#include <math.h>

#define NLEVEL 16
#define TSIZE 16384

struct NsParam { int n[NLEVEL]; };

__global__ __launch_bounds__(256) void nerf_fused(
    const float* __restrict__ x,
    const float* __restrict__ embed,
    const float* __restrict__ dW0, const float* __restrict__ db0,
    const float* __restrict__ dW1, const float* __restrict__ db1,
    const float* __restrict__ cW0, const float* __restrict__ cb0,
    const float* __restrict__ cW1, const float* __restrict__ cb1,
    const float* __restrict__ cW2, const float* __restrict__ cb2,
    float* __restrict__ out, int B, NsParam ns)
{
    int idx = blockIdx.x * blockDim.x + threadIdx.x;
    if (idx >= B) return;

    const float* xp = x + (long long)idx * 6;
    float px = xp[0], py = xp[1], pz = xp[2];
    float vx = xp[3], vy = xp[4], vz = xp[5];

    float cx = fminf(fmaxf((px + 5.0f) / 10.0f, 0.0f), 0.999999f);
    float cy = fminf(fmaxf((py + 5.0f) / 10.0f, 0.0f), 0.999999f);
    float cz = fminf(fmaxf((pz + 5.0f) / 10.0f, 0.0f), 0.999999f);

    // ---- density MLP layer 0 accumulator (32 -> 64), fused with encode ----
    float h64[64];
    #pragma unroll
    for (int j = 0; j < 64; ++j) h64[j] = db0[j];

    #pragma unroll
    for (int l = 0; l < NLEVEL; ++l) {
        int n = ns.n[l];
        float fn = (float)n;
        float xl0 = cx * fn, xl1 = cy * fn, xl2 = cz * fn;
        float f0 = floorf(xl0), f1 = floorf(xl1), f2 = floorf(xl2);
        int i0 = (int)f0, i1 = (int)f1, i2 = (int)f2;
        float w0 = xl0 - f0, w1 = xl1 - f1, w2 = xl2 - f2;
        const float* eb = embed + l * (TSIZE * 2);
        int np1 = n + 1;
        bool dense = (np1 * np1 * np1 <= TSIZE);

        float a0 = 0.0f, a1 = 0.0f;
        #pragma unroll
        for (int c = 0; c < 8; ++c) {
            int o0 = (c >> 2) & 1, o1 = (c >> 1) & 1, o2 = c & 1;
            int ind;
            if (dense) {
                ind = (i0 + o0) * np1 * np1 + (i1 + o1) * np1 + (i2 + o2);
            } else {
                unsigned h = (unsigned)(i0 + o0) * 1u
                           ^ (unsigned)(i1 + o1) * 2654435761u
                           ^ (unsigned)(i2 + o2) * 805459861u;
                ind = (int)(h & (TSIZE - 1));
            }
            float ww = (o0 ? w0 : 1.0f - w0)
                     * (o1 ? w1 : 1.0f - w1)
                     * (o2 ? w2 : 1.0f - w2);
            const float2 fe = *(const float2*)(eb + (long long)ind * 2);
            a0 = fmaf(fe.x, ww, a0);
            a1 = fmaf(fe.y, ww, a1);
        }
        // accumulate features (pts[2l], pts[2l+1]) into h64 via rows of dW0
        const float* wr0 = dW0 + (2 * l) * 64;
        const float* wr1 = dW0 + (2 * l + 1) * 64;
        #pragma unroll
        for (int j = 0; j < 64; ++j) {
            h64[j] = fmaf(a0, wr0[j], fmaf(a1, wr1[j], h64[j]));
        }
    }

    // ---- density MLP layer 1: h16 = relu(h64) @ dW1 + db1 ----
    float h16[16];
    #pragma unroll
    for (int k = 0; k < 16; ++k) h16[k] = db1[k];
    #pragma unroll
    for (int j = 0; j < 64; ++j) {
        float a = fmaxf(h64[j], 0.0f);
        const float* wr = dW1 + j * 16;
        #pragma unroll
        for (int k = 0; k < 16; ++k) h16[k] = fmaf(a, wr[k], h16[k]);
    }

    float density = 1.0f / (1.0f + expf(-h16[0]));

    // ---- color input: [density, relu(h16[1..15]), view] (19) ----
    float cin[19];
    cin[0] = density;
    #pragma unroll
    for (int k = 1; k < 16; ++k) cin[k] = fmaxf(h16[k], 0.0f);
    cin[16] = vx; cin[17] = vy; cin[18] = vz;

    // ---- color layer 0: 19 -> 64, relu ----
    float c1[64];
    #pragma unroll
    for (int j = 0; j < 64; ++j) c1[j] = cb0[j];
    #pragma unroll
    for (int i = 0; i < 19; ++i) {
        const float* wr = cW0 + i * 64;
        float a = cin[i];
        #pragma unroll
        for (int j = 0; j < 64; ++j) c1[j] = fmaf(a, wr[j], c1[j]);
    }
    #pragma unroll
    for (int j = 0; j < 64; ++j) c1[j] = fmaxf(c1[j], 0.0f);

    // ---- color layer 1: 64 -> 64, relu (fused with cW2 reduction below) ----
    float c2[64];
    #pragma unroll
    for (int j = 0; j < 64; ++j) c2[j] = cb1[j];
    #pragma unroll
    for (int i = 0; i < 64; ++i) {
        const float* wr = cW1 + i * 64;
        float a = c1[i];
        #pragma unroll
        for (int j = 0; j < 64; ++j) c2[j] = fmaf(a, wr[j], c2[j]);
    }

    // ---- color layer 2: 64 -> 3, sigmoid ----
    float col0 = cb2[0], col1 = cb2[1], col2 = cb2[2];
    #pragma unroll
    for (int j = 0; j < 64; ++j) {
        float a = fmaxf(c2[j], 0.0f);
        col0 = fmaf(a, cW2[j * 3 + 0], col0);
        col1 = fmaf(a, cW2[j * 3 + 1], col1);
        col2 = fmaf(a, cW2[j * 3 + 2], col2);
    }

    float4 o;
    o.x = density;
    o.y = 1.0f / (1.0f + expf(-col0));
    o.z = 1.0f / (1.0f + expf(-col1));
    o.w = 1.0f / (1.0f + expf(-col2));
    *(float4*)(out + (long long)idx * 4) = o;
}

extern "C" void kernel_launch(void* const* d_in, const int* in_sizes, int n_in,
                              void* d_out, int out_size, void* d_ws, size_t ws_size,
                              hipStream_t stream) {
    const float* x    = (const float*)d_in[0];
    const float* embed= (const float*)d_in[1];
    const float* dW0  = (const float*)d_in[2];
    const float* db0  = (const float*)d_in[3];
    const float* dW1  = (const float*)d_in[4];
    const float* db1  = (const float*)d_in[5];
    const float* cW0  = (const float*)d_in[6];
    const float* cb0  = (const float*)d_in[7];
    const float* cW1  = (const float*)d_in[8];
    const float* cb1  = (const float*)d_in[9];
    const float* cW2  = (const float*)d_in[10];
    const float* cb2  = (const float*)d_in[11];
    float* out = (float*)d_out;

    int B = in_sizes[0] / 6;

    // Replicate numpy's NS computation bit-for-bit (same libm on this host):
    // B_GROWTH = exp((log(512)-log(16))/15); NS[l] = int(16 * B_GROWTH**l)
    NsParam ns;
    double g = exp((log(512.0) - log(16.0)) / 15.0);
    for (int i = 0; i < NLEVEL; ++i) {
        ns.n[i] = (int)(16.0 * pow(g, (double)i));
    }

    int block = 256;
    int grid = (B + block - 1) / block;
    nerf_fused<<<grid, block, 0, stream>>>(x, embed,
        dW0, db0, dW1, db1, cW0, cb0, cW1, cb1, cW2, cb2,
        out, B, ns);
}

// Round 2
// 1772.751 us; speedup vs baseline: 1.3044x; 1.3044x over previous
//
#include <hip/hip_runtime.h>
#include <math.h>

#define NLEVEL 16
#define TSIZE 16384

struct NsParam { int n[NLEVEL]; };

// Force wave-uniform weight loads through the scalar unit (s_load) by
// casting to the constant address space. Weights addresses are uniform,
// so this turns every weight access into s_load_dwordx{4,8,16} + v_fmac v,s,v.
typedef const __attribute__((address_space(4))) float* cfp;
__device__ __forceinline__ cfp cc(const float* p) {
    return (cfp)(unsigned long long)p;
}

__global__ __launch_bounds__(256, 4) void nerf_fused(
    const float* __restrict__ x,
    const float* __restrict__ embed,
    const float* __restrict__ dW0, const float* __restrict__ db0,
    const float* __restrict__ dW1, const float* __restrict__ db1,
    const float* __restrict__ cW0, const float* __restrict__ cb0,
    const float* __restrict__ cW1, const float* __restrict__ cb1,
    const float* __restrict__ cW2, const float* __restrict__ cb2,
    float* __restrict__ out, int B, NsParam ns)
{
    int idx = blockIdx.x * blockDim.x + threadIdx.x;
    if (idx >= B) return;

    cfp DW0 = cc(dW0), DB0 = cc(db0), DW1 = cc(dW1), DB1 = cc(db1);
    cfp CW0 = cc(cW0), CB0 = cc(cb0), CW1 = cc(cW1), CB1 = cc(cb1);
    cfp CW2 = cc(cW2), CB2 = cc(cb2);

    const float* xp = x + (long long)idx * 6;
    float px = xp[0], py = xp[1], pz = xp[2];
    float vx = xp[3], vy = xp[4], vz = xp[5];

    float cx = fminf(fmaxf((px + 5.0f) / 10.0f, 0.0f), 0.999999f);
    float cy = fminf(fmaxf((py + 5.0f) / 10.0f, 0.0f), 0.999999f);
    float cz = fminf(fmaxf((pz + 5.0f) / 10.0f, 0.0f), 0.999999f);

    // ---- density MLP layer 0 accumulator (32 -> 64), fused with encode ----
    float h64[64];
    #pragma unroll
    for (int j = 0; j < 64; ++j) h64[j] = DB0[j];

    #pragma unroll
    for (int l = 0; l < NLEVEL; ++l) {
        int n = ns.n[l];
        float fn = (float)n;
        float xl0 = cx * fn, xl1 = cy * fn, xl2 = cz * fn;
        float f0 = floorf(xl0), f1 = floorf(xl1), f2 = floorf(xl2);
        int i0 = (int)f0, i1 = (int)f1, i2 = (int)f2;
        float w0 = xl0 - f0, w1 = xl1 - f1, w2 = xl2 - f2;
        const float* eb = embed + l * (TSIZE * 2);
        int np1 = n + 1;
        bool dense = (np1 * np1 * np1 <= TSIZE);

        // Issue all 8 gathers first, then combine (lets scheduler overlap).
        float2 fe[8];
        #pragma unroll
        for (int c = 0; c < 8; ++c) {
            int o0 = (c >> 2) & 1, o1 = (c >> 1) & 1, o2 = c & 1;
            int ind;
            if (dense) {
                ind = (i0 + o0) * np1 * np1 + (i1 + o1) * np1 + (i2 + o2);
            } else {
                unsigned h = (unsigned)(i0 + o0) * 1u
                           ^ (unsigned)(i1 + o1) * 2654435761u
                           ^ (unsigned)(i2 + o2) * 805459861u;
                ind = (int)(h & (TSIZE - 1));
            }
            fe[c] = *(const float2*)(eb + (long long)ind * 2);
        }
        float a0 = 0.0f, a1 = 0.0f;
        #pragma unroll
        for (int c = 0; c < 8; ++c) {
            int o0 = (c >> 2) & 1, o1 = (c >> 1) & 1, o2 = c & 1;
            float ww = (o0 ? w0 : 1.0f - w0)
                     * (o1 ? w1 : 1.0f - w1)
                     * (o2 ? w2 : 1.0f - w2);
            a0 = fmaf(fe[c].x, ww, a0);
            a1 = fmaf(fe[c].y, ww, a1);
        }
        // accumulate features (pts[2l], pts[2l+1]) into h64 via rows of dW0
        cfp wr0 = DW0 + (2 * l) * 64;
        cfp wr1 = DW0 + (2 * l + 1) * 64;
        #pragma unroll
        for (int j = 0; j < 64; ++j) {
            h64[j] = fmaf(a0, wr0[j], fmaf(a1, wr1[j], h64[j]));
        }
    }

    // ---- density MLP layer 1: h16 = relu(h64) @ dW1 + db1 ----
    float h16[16];
    #pragma unroll
    for (int k = 0; k < 16; ++k) h16[k] = DB1[k];
    #pragma unroll
    for (int j = 0; j < 64; ++j) {
        float a = fmaxf(h64[j], 0.0f);
        cfp wr = DW1 + j * 16;
        #pragma unroll
        for (int k = 0; k < 16; ++k) h16[k] = fmaf(a, wr[k], h16[k]);
    }

    float density = 1.0f / (1.0f + expf(-h16[0]));

    // ---- color input: [density, relu(h16[1..15]), view] (19) ----
    float cin[19];
    cin[0] = density;
    #pragma unroll
    for (int k = 1; k < 16; ++k) cin[k] = fmaxf(h16[k], 0.0f);
    cin[16] = vx; cin[17] = vy; cin[18] = vz;

    // ---- color layer 0: 19 -> 64, relu ----
    float c1[64];
    #pragma unroll
    for (int j = 0; j < 64; ++j) c1[j] = CB0[j];
    #pragma unroll
    for (int i = 0; i < 19; ++i) {
        cfp wr = CW0 + i * 64;
        float a = cin[i];
        #pragma unroll
        for (int j = 0; j < 64; ++j) c1[j] = fmaf(a, wr[j], c1[j]);
    }
    #pragma unroll
    for (int j = 0; j < 64; ++j) c1[j] = fmaxf(c1[j], 0.0f);

    // ---- color layers 1+2 fused, chunked to cap VGPR pressure ----
    // c2 computed 16 outputs at a time; each chunk immediately reduced
    // through relu + cW2 into the 3 color accumulators, then freed.
    float col0 = CB2[0] + 0.0f, col1 = CB2[1] + 0.0f, col2 = CB2[2] + 0.0f;
    // NOTE: cb2 added first, matching reference bias-then-accumulate order.
    col0 = CB2[0]; col1 = CB2[1]; col2 = CB2[2];
    #pragma unroll
    for (int k = 0; k < 4; ++k) {
        float c2k[16];
        #pragma unroll
        for (int j = 0; j < 16; ++j) c2k[j] = CB1[k * 16 + j];
        #pragma unroll
        for (int i = 0; i < 64; ++i) {
            float a = c1[i];
            cfp wr = CW1 + i * 64 + k * 16;
            #pragma unroll
            for (int j = 0; j < 16; ++j) c2k[j] = fmaf(a, wr[j], c2k[j]);
        }
        #pragma unroll
        for (int j = 0; j < 16; ++j) {
            float a = fmaxf(c2k[j], 0.0f);
            int jj = k * 16 + j;
            col0 = fmaf(a, CW2[jj * 3 + 0], col0);
            col1 = fmaf(a, CW2[jj * 3 + 1], col1);
            col2 = fmaf(a, CW2[jj * 3 + 2], col2);
        }
    }

    float4 o;
    o.x = density;
    o.y = 1.0f / (1.0f + expf(-col0));
    o.z = 1.0f / (1.0f + expf(-col1));
    o.w = 1.0f / (1.0f + expf(-col2));
    *(float4*)(out + (long long)idx * 4) = o;
}

extern "C" void kernel_launch(void* const* d_in, const int* in_sizes, int n_in,
                              void* d_out, int out_size, void* d_ws, size_t ws_size,
                              hipStream_t stream) {
    const float* x    = (const float*)d_in[0];
    const float* embed= (const float*)d_in[1];
    const float* dW0  = (const float*)d_in[2];
    const float* db0  = (const float*)d_in[3];
    const float* dW1  = (const float*)d_in[4];
    const float* db1  = (const float*)d_in[5];
    const float* cW0  = (const float*)d_in[6];
    const float* cb0  = (const float*)d_in[7];
    const float* cW1  = (const float*)d_in[8];
    const float* cb1  = (const float*)d_in[9];
    const float* cW2  = (const float*)d_in[10];
    const float* cb2  = (const float*)d_in[11];
    float* out = (float*)d_out;

    int B = in_sizes[0] / 6;

    // Replicate numpy's NS computation bit-for-bit (same libm on this host):
    // B_GROWTH = exp((log(512)-log(16))/15); NS[l] = int(16 * B_GROWTH**l)
    NsParam ns;
    double g = exp((log(512.0) - log(16.0)) / 15.0);
    for (int i = 0; i < NLEVEL; ++i) {
        ns.n[i] = (int)(16.0 * pow(g, (double)i));
    }

    int block = 256;
    int grid = (B + block - 1) / block;
    nerf_fused<<<grid, block, 0, stream>>>(x, embed,
        dW0, db0, dW1, db1, cW0, cb0, cW1, cb1, cW2, cb2,
        out, B, ns);
}